// Round 1
// baseline (2780.378 us; speedup 1.0000x reference)
//
#include <hip/hip_runtime.h>

// Problem constants (from reference): B=4, S=2048, H=1024, I=2816, E=8
#define MDIM 8192   // B*S
#define HDIM 1024
#define IDIM 2816
#define NEXP 8

typedef __bf16 bf16;
typedef __attribute__((ext_vector_type(8))) __bf16 bf16x8;
typedef __attribute__((ext_vector_type(4))) float f32x4;

// ---- async global->LDS, 16B per lane. LDS dest is wave-uniform base + lane*16.
__device__ __forceinline__ void gload16(const void* g, void* l) {
  __builtin_amdgcn_global_load_lds(
      (const __attribute__((address_space(1))) void*)g,
      (__attribute__((address_space(3))) void*)l, 16, 0, 0);
}

__device__ __forceinline__ f32x4 mfma16(bf16x8 a, bf16x8 b, f32x4 c) {
  return __builtin_amdgcn_mfma_f32_16x16x32_bf16(a, b, c, 0, 0, 0);
}

// ---------------- hs f32 -> bf16 (vectorized: 8 elems/thread) ----------------
__global__ __launch_bounds__(256) void convert_hs_kernel(
    const float* __restrict__ in, bf16* __restrict__ out) {
  size_t i = (size_t)blockIdx.x * 256 + threadIdx.x;   // i < MDIM*HDIM/8
  const f32x4* p = (const f32x4*)in + i * 2;
  f32x4 a = p[0], b = p[1];
  bf16x8 o;
  o[0] = (bf16)a[0]; o[1] = (bf16)a[1]; o[2] = (bf16)a[2]; o[3] = (bf16)a[3];
  o[4] = (bf16)b[0]; o[5] = (bf16)b[1]; o[6] = (bf16)b[2]; o[7] = (bf16)b[3];
  *((bf16x8*)out + i) = o;
}

// ---------------- router: logits + softmax, fp32, one wave per token ---------
__global__ __launch_bounds__(256) void router_kernel(
    const float* __restrict__ hs, const float* __restrict__ rww,
    const float* __restrict__ rwb, float* __restrict__ out) {
  const int lane = threadIdx.x & 63;
  const int wv = threadIdx.x >> 6;
  const size_t row = (size_t)blockIdx.x * 4 + wv;   // < MDIM
  const float* h = hs + row * HDIM;
  float logit[NEXP];
#pragma unroll
  for (int e = 0; e < NEXP; ++e) {
    const float* w = rww + e * HDIM;
    float s = 0.f;
    for (int k = lane; k < HDIM; k += 64) s += h[k] * w[k];
#pragma unroll
    for (int o = 32; o > 0; o >>= 1) s += __shfl_xor(s, o);
    logit[e] = s + rwb[e];
  }
  float mx = logit[0];
#pragma unroll
  for (int e = 1; e < NEXP; ++e) mx = fmaxf(mx, logit[e]);
  float den = 0.f, ex[NEXP];
#pragma unroll
  for (int e = 0; e < NEXP; ++e) { ex[e] = __expf(logit[e] - mx); den += ex[e]; }
  float inv = 1.f / den;
  if (lane == 0) {
#pragma unroll
    for (int e = 0; e < NEXP; ++e) out[row * NEXP + e] = ex[e] * inv;
  }
}

// ---------------- balance loss (single block) --------------------------------
__global__ __launch_bounds__(256) void balance_kernel(
    const float* __restrict__ rw, float* __restrict__ loss) {
  const int SE = 2048 * NEXP;  // 16384; batch stride in rw = S*E = 16384
  float s = 0.f;
  for (int idx = threadIdx.x; idx < SE; idx += 256) {
    float m = (rw[idx] + rw[idx + 16384] + rw[idx + 32768] + rw[idx + 49152]) * 0.25f;
    float d = m - 0.125f;
    s += d * d;
  }
#pragma unroll
  for (int o = 32; o > 0; o >>= 1) s += __shfl_xor(s, o);
  __shared__ float red[4];
  if ((threadIdx.x & 63) == 0) red[threadIdx.x >> 6] = s;
  __syncthreads();
  if (threadIdx.x == 0)
    loss[0] = (red[0] + red[1] + red[2] + red[3]) * (0.01f / 16384.f);
}

// ---------------- transpose + f32->bf16:  in[R][C] -> out[c*ld_out + r] ------
__global__ void transpose_conv_kernel(const float* __restrict__ in,
                                      bf16* __restrict__ out,
                                      int R, int C, int ld_out) {
  __shared__ float tile[32][33];
  const int c0 = blockIdx.x * 32, r0 = blockIdx.y * 32;
  const int tx = threadIdx.x, ty = threadIdx.y;   // block (32,8)
#pragma unroll
  for (int i = 0; i < 4; ++i)
    tile[ty + i * 8][tx] = in[(size_t)(r0 + ty + i * 8) * C + c0 + tx];
  __syncthreads();
#pragma unroll
  for (int i = 0; i < 4; ++i)
    out[(size_t)(c0 + ty + i * 8) * ld_out + r0 + tx] = (bf16)tile[tx][ty + i * 8];
}

// ---------------- fused gate/up GEMM -----------------------------------------
// A[M][HDIM] bf16, Gt/Ut[N][HDIM] bf16 (pre-transposed). Writes
// out[row*ldout + col] = silu(A@G) * (A@U) * rw[row*8]  as bf16.
__global__ __launch_bounds__(256) void gemm_gu_kernel(
    const bf16* __restrict__ A, const bf16* __restrict__ Gt,
    const bf16* __restrict__ Ut, const float* __restrict__ rwp,
    bf16* __restrict__ out, int ldout) {
  constexpr int BK = 32;
  __shared__ __align__(16) bf16 As[128 * BK];
  __shared__ __align__(16) bf16 Gs[128 * BK];
  __shared__ __align__(16) bf16 Us[128 * BK];
  const int t = threadIdx.x;
  const int lane = t & 63;
  const int wr = (t >> 7) & 1, wc = (t >> 6) & 1;
  const size_t bm = (size_t)blockIdx.x * 128;
  const size_t bn = (size_t)blockIdx.y * 128;
  const int srow = t >> 2, skc = (t & 3) * 8;
  const bf16* pa = A + (bm + srow) * HDIM + skc;
  const bf16* pg = Gt + (bn + srow) * HDIM + skc;
  const bf16* pu = Ut + (bn + srow) * HDIM + skc;
  bf16* lA = As + t * 8;  // byte offset t*16 == linear tile [row][k]
  bf16* lG = Gs + t * 8;
  bf16* lU = Us + t * 8;
  const int fr = lane & 15, fq = lane >> 4;

  f32x4 ag[4][4] = {};
  f32x4 au[4][4] = {};

  for (int k0 = 0; k0 < HDIM; k0 += BK) {
    gload16(pa + k0, lA);
    gload16(pa + 64 * HDIM + k0, lA + 2048);
    gload16(pg + k0, lG);
    gload16(pg + 64 * HDIM + k0, lG + 2048);
    gload16(pu + k0, lU);
    gload16(pu + 64 * HDIM + k0, lU + 2048);
    __syncthreads();   // compiler drains vmcnt before s_barrier
    bf16x8 af[4], gf[4], uf[4];
#pragma unroll
    for (int m = 0; m < 4; ++m)
      af[m] = *(const bf16x8*)(As + (wr * 64 + m * 16 + fr) * BK + fq * 8);
#pragma unroll
    for (int n = 0; n < 4; ++n) {
      gf[n] = *(const bf16x8*)(Gs + (wc * 64 + n * 16 + fr) * BK + fq * 8);
      uf[n] = *(const bf16x8*)(Us + (wc * 64 + n * 16 + fr) * BK + fq * 8);
    }
#pragma unroll
    for (int m = 0; m < 4; ++m)
#pragma unroll
      for (int n = 0; n < 4; ++n) {
        ag[m][n] = mfma16(af[m], gf[n], ag[m][n]);
        au[m][n] = mfma16(af[m], uf[n], au[m][n]);
      }
    __syncthreads();
  }

  // epilogue: C/D layout col=lane&15, row=(lane>>4)*4+reg (m89-verified)
#pragma unroll
  for (int m = 0; m < 4; ++m) {
    const size_t rbase = bm + wr * 64 + m * 16 + fq * 4;
    float rwv[4];
#pragma unroll
    for (int j = 0; j < 4; ++j) rwv[j] = rwp[(rbase + j) * NEXP];
#pragma unroll
    for (int n = 0; n < 4; ++n) {
      const size_t col = bn + wc * 64 + n * 16 + fr;
#pragma unroll
      for (int j = 0; j < 4; ++j) {
        float g = ag[m][n][j];
        float u = au[m][n][j];
        float sil = g / (1.f + __expf(-g));
        out[(rbase + j) * (size_t)ldout + col] = (bf16)(sil * u * rwv[j]);
      }
    }
  }
}

// ---------------- down GEMM: out[M][1024] (+)= A[M][K] @ Bt[1024][K]^T -------
__global__ __launch_bounds__(256) void gemm_down_kernel(
    const bf16* __restrict__ A, int lda, const bf16* __restrict__ Bt, int ldb,
    float* __restrict__ out, int K, int accumulate) {
  constexpr int BK = 32;
  __shared__ __align__(16) bf16 As[128 * BK];
  __shared__ __align__(16) bf16 Bs[128 * BK];
  const int t = threadIdx.x;
  const int lane = t & 63;
  const int wr = (t >> 7) & 1, wc = (t >> 6) & 1;
  const size_t bm = (size_t)blockIdx.x * 128;
  const size_t bn = (size_t)blockIdx.y * 128;
  const int srow = t >> 2, skc = (t & 3) * 8;
  const bf16* pa = A + (bm + srow) * (size_t)lda + skc;
  const bf16* pb = Bt + (bn + srow) * (size_t)ldb + skc;
  bf16* lA = As + t * 8;
  bf16* lB = Bs + t * 8;
  const int fr = lane & 15, fq = lane >> 4;

  f32x4 acc[4][4] = {};

  for (int k0 = 0; k0 < K; k0 += BK) {
    gload16(pa + k0, lA);
    gload16(pa + (size_t)64 * lda + k0, lA + 2048);
    gload16(pb + k0, lB);
    gload16(pb + (size_t)64 * ldb + k0, lB + 2048);
    __syncthreads();
    bf16x8 af[4], bfr[4];
#pragma unroll
    for (int m = 0; m < 4; ++m)
      af[m] = *(const bf16x8*)(As + (wr * 64 + m * 16 + fr) * BK + fq * 8);
#pragma unroll
    for (int n = 0; n < 4; ++n)
      bfr[n] = *(const bf16x8*)(Bs + (wc * 64 + n * 16 + fr) * BK + fq * 8);
#pragma unroll
    for (int m = 0; m < 4; ++m)
#pragma unroll
      for (int n = 0; n < 4; ++n)
        acc[m][n] = mfma16(af[m], bfr[n], acc[m][n]);
    __syncthreads();
  }

#pragma unroll
  for (int m = 0; m < 4; ++m) {
    const size_t rbase = bm + wr * 64 + m * 16 + fq * 4;
#pragma unroll
    for (int n = 0; n < 4; ++n) {
      const size_t col = bn + wc * 64 + n * 16 + fr;
#pragma unroll
      for (int j = 0; j < 4; ++j) {
        const size_t o = (rbase + j) * (size_t)HDIM + col;
        float v = acc[m][n][j];
        out[o] = accumulate ? (out[o] + v) : v;
      }
    }
  }
}

// -----------------------------------------------------------------------------
extern "C" void kernel_launch(void* const* d_in, const int* in_sizes, int n_in,
                              void* d_out, int out_size, void* d_ws, size_t ws_size,
                              hipStream_t stream) {
  const float* hs       = (const float*)d_in[0];
  const float* router_w = (const float*)d_in[1];
  const float* router_b = (const float*)d_in[2];
  const float* gate_w   = (const float*)d_in[3];
  const float* up_w     = (const float*)d_in[4];
  const float* down_w   = (const float*)d_in[5];
  float* out = (float*)d_out;

  const size_t KALL = (size_t)NEXP * IDIM;  // 22528

  char* ws = (char*)d_ws;
  size_t off = 0;
  auto alloc = [&](size_t bytes) -> void* {
    void* p = ws + off;
    off += (bytes + 255) & ~(size_t)255;
    return p;
  };

  float* rw    = (float*)alloc((size_t)MDIM * NEXP * 4);
  bf16* hsb    = (bf16*)alloc((size_t)MDIM * HDIM * 2);
  bf16* gate_t = (bf16*)alloc((size_t)IDIM * HDIM * 2);
  bf16* up_t   = (bf16*)alloc((size_t)IDIM * HDIM * 2);

  const size_t prefix = off;
  const size_t needA = prefix + (((size_t)HDIM * KALL * 2 + 255) & ~(size_t)255)
                              + (((size_t)MDIM * KALL * 2 + 255) & ~(size_t)255);
  const bool planA = (ws_size >= needA);

  // common: convert hs, router softmax, balance loss
  convert_hs_kernel<<<dim3((MDIM * HDIM) / (256 * 8)), dim3(256), 0, stream>>>(hs, hsb);
  router_kernel<<<dim3(MDIM / 4), dim3(256), 0, stream>>>(hs, router_w, router_b, rw);
  balance_kernel<<<dim3(1), dim3(256), 0, stream>>>(rw, out + (size_t)MDIM * HDIM);

  if (planA) {
    // single big-K down GEMM over concatenated (rw-scaled) gu'
    bf16* down_t = (bf16*)alloc((size_t)HDIM * KALL * 2);  // [H][E*I]
    bf16* gu     = (bf16*)alloc((size_t)MDIM * KALL * 2);  // [M][E*I]
    for (int e = 0; e < NEXP; ++e) {
      transpose_conv_kernel<<<dim3(IDIM / 32, HDIM / 32), dim3(32, 8), 0, stream>>>(
          gate_w + (size_t)e * HDIM * IDIM, gate_t, HDIM, IDIM, HDIM);
      transpose_conv_kernel<<<dim3(IDIM / 32, HDIM / 32), dim3(32, 8), 0, stream>>>(
          up_w + (size_t)e * HDIM * IDIM, up_t, HDIM, IDIM, HDIM);
      transpose_conv_kernel<<<dim3(HDIM / 32, IDIM / 32), dim3(32, 8), 0, stream>>>(
          down_w + (size_t)e * IDIM * HDIM, down_t + (size_t)e * IDIM, IDIM, HDIM, (int)KALL);
      gemm_gu_kernel<<<dim3(MDIM / 128, IDIM / 128), dim3(256), 0, stream>>>(
          hsb, gate_t, up_t, rw + e, gu + (size_t)e * IDIM, (int)KALL);
    }
    gemm_down_kernel<<<dim3(MDIM / 128, HDIM / 128), dim3(256), 0, stream>>>(
        gu, (int)KALL, down_t, (int)KALL, out, (int)KALL, 0);
  } else {
    // sequential experts, accumulate into memset output
    bf16* down_ts = (bf16*)alloc((size_t)HDIM * IDIM * 2);  // [H][I]
    bf16* gu      = (bf16*)alloc((size_t)MDIM * IDIM * 2);  // [M][I]
    hipMemsetAsync(out, 0, (size_t)MDIM * HDIM * 4, stream);
    for (int e = 0; e < NEXP; ++e) {
      transpose_conv_kernel<<<dim3(IDIM / 32, HDIM / 32), dim3(32, 8), 0, stream>>>(
          gate_w + (size_t)e * HDIM * IDIM, gate_t, HDIM, IDIM, HDIM);
      transpose_conv_kernel<<<dim3(IDIM / 32, HDIM / 32), dim3(32, 8), 0, stream>>>(
          up_w + (size_t)e * HDIM * IDIM, up_t, HDIM, IDIM, HDIM);
      transpose_conv_kernel<<<dim3(HDIM / 32, IDIM / 32), dim3(32, 8), 0, stream>>>(
          down_w + (size_t)e * IDIM * HDIM, down_ts, IDIM, HDIM, IDIM);
      gemm_gu_kernel<<<dim3(MDIM / 128, IDIM / 128), dim3(256), 0, stream>>>(
          hsb, gate_t, up_t, rw + e, gu, IDIM);
      gemm_down_kernel<<<dim3(MDIM / 128, HDIM / 128), dim3(256), 0, stream>>>(
          gu, IDIM, down_ts, IDIM, out, IDIM, 1);
    }
  }
  (void)in_sizes; (void)n_in; (void)out_size;
}

// Round 3
// 1893.458 us; speedup vs baseline: 1.4684x; 1.4684x over previous
//
#include <hip/hip_runtime.h>

// Problem constants (from reference): B=4, S=2048, H=1024, I=2816, E=8
#define MDIM 8192   // B*S
#define HDIM 1024
#define IDIM 2816
#define NEXP 8

typedef __bf16 bf16;
typedef __attribute__((ext_vector_type(8))) __bf16 bf16x8;
typedef __attribute__((ext_vector_type(4))) float f32x4;

// ---- async global->LDS, 16B per lane. LDS dest is wave-uniform base + lane*16.
__device__ __forceinline__ void gload16(const void* g, void* l) {
  __builtin_amdgcn_global_load_lds(
      (const __attribute__((address_space(1))) void*)g,
      (__attribute__((address_space(3))) void*)l, 16, 0, 0);
}

__device__ __forceinline__ f32x4 mfma16(bf16x8 a, bf16x8 b, f32x4 c) {
  return __builtin_amdgcn_mfma_f32_16x16x32_bf16(a, b, c, 0, 0, 0);
}

// bijective XCD swizzle (m204): nwg need not be %8 but formula handles it
__device__ __forceinline__ int xcd_swizzle(int orig, int nwg) {
  int q = nwg >> 3, r = nwg & 7;
  int x = orig & 7, w = orig >> 3;
  return (x < r ? x * (q + 1) : r * (q + 1) + (x - r) * q) + w;
}

// ---------------- hs f32 -> bf16 (vectorized: 8 elems/thread) ----------------
__global__ __launch_bounds__(256) void convert_hs_kernel(
    const float* __restrict__ in, bf16* __restrict__ out) {
  size_t i = (size_t)blockIdx.x * 256 + threadIdx.x;   // i < MDIM*HDIM/8
  const f32x4* p = (const f32x4*)in + i * 2;
  f32x4 a = p[0], b = p[1];
  bf16x8 o;
  o[0] = (bf16)a[0]; o[1] = (bf16)a[1]; o[2] = (bf16)a[2]; o[3] = (bf16)a[3];
  o[4] = (bf16)b[0]; o[5] = (bf16)b[1]; o[6] = (bf16)b[2]; o[7] = (bf16)b[3];
  *((bf16x8*)out + i) = o;
}

// ---------------- router: logits + softmax, fp32, one wave per token ---------
__global__ __launch_bounds__(256) void router_kernel(
    const float* __restrict__ hs, const float* __restrict__ rww,
    const float* __restrict__ rwb, float* __restrict__ out) {
  const int lane = threadIdx.x & 63;
  const int wv = threadIdx.x >> 6;
  const size_t row = (size_t)blockIdx.x * 4 + wv;   // < MDIM
  const float* h = hs + row * HDIM;
  float logit[NEXP];
#pragma unroll
  for (int e = 0; e < NEXP; ++e) {
    const float* w = rww + e * HDIM;
    float s = 0.f;
    for (int k = lane; k < HDIM; k += 64) s += h[k] * w[k];
#pragma unroll
    for (int o = 32; o > 0; o >>= 1) s += __shfl_xor(s, o);
    logit[e] = s + rwb[e];
  }
  float mx = logit[0];
#pragma unroll
  for (int e = 1; e < NEXP; ++e) mx = fmaxf(mx, logit[e]);
  float den = 0.f, ex[NEXP];
#pragma unroll
  for (int e = 0; e < NEXP; ++e) { ex[e] = __expf(logit[e] - mx); den += ex[e]; }
  float inv = 1.f / den;
  if (lane == 0) {
#pragma unroll
    for (int e = 0; e < NEXP; ++e) out[row * NEXP + e] = ex[e] * inv;
  }
}

// ---------------- balance loss (single block) --------------------------------
__global__ __launch_bounds__(256) void balance_kernel(
    const float* __restrict__ rw, float* __restrict__ loss) {
  const int SE = 2048 * NEXP;  // 16384; batch stride in rw = S*E = 16384
  float s = 0.f;
  for (int idx = threadIdx.x; idx < SE; idx += 256) {
    float m = (rw[idx] + rw[idx + 16384] + rw[idx + 32768] + rw[idx + 49152]) * 0.25f;
    float d = m - 0.125f;
    s += d * d;
  }
#pragma unroll
  for (int o = 32; o > 0; o >>= 1) s += __shfl_xor(s, o);
  __shared__ float red[4];
  if ((threadIdx.x & 63) == 0) red[threadIdx.x >> 6] = s;
  __syncthreads();
  if (threadIdx.x == 0)
    loss[0] = (red[0] + red[1] + red[2] + red[3]) * (0.01f / 16384.f);
}

// ---------------- transpose + f32->bf16:  in[R][C] -> out[c*ld_out + r] ------
__global__ void transpose_conv_kernel(const float* __restrict__ in,
                                      bf16* __restrict__ out,
                                      int R, int C, int ld_out) {
  __shared__ float tile[32][33];
  const int c0 = blockIdx.x * 32, r0 = blockIdx.y * 32;
  const int tx = threadIdx.x, ty = threadIdx.y;   // block (32,8)
#pragma unroll
  for (int i = 0; i < 4; ++i)
    tile[ty + i * 8][tx] = in[(size_t)(r0 + ty + i * 8) * C + c0 + tx];
  __syncthreads();
#pragma unroll
  for (int i = 0; i < 4; ++i)
    out[(size_t)(c0 + ty + i * 8) * ld_out + r0 + tx] = (bf16)tile[tx][ty + i * 8];
}

// ---------------- fused gate/up GEMM (128x128 tile, 8 waves, dbuf prefetch) --
// A[M][HDIM] bf16, Gt/Ut[N][HDIM] bf16 (pre-transposed). Writes
// out[row*ldout + col] = silu(A@G) * (A@U) * rw[row*8]  as bf16.
__global__ __launch_bounds__(512, 4) void gemm_gu_kernel(
    const bf16* __restrict__ A, const bf16* __restrict__ Gt,
    const bf16* __restrict__ Ut, const float* __restrict__ rwp,
    bf16* __restrict__ out, int ldout) {
  constexpr int BK = 32;
  constexpr int NT = HDIM / BK;  // 32
  __shared__ __align__(16) bf16 As[2][128 * BK];
  __shared__ __align__(16) bf16 Gs[2][128 * BK];
  __shared__ __align__(16) bf16 Us[2][128 * BK];
  const int t = threadIdx.x;
  const int lane = t & 63;
  const int wid = t >> 6;               // 0..7
  const int wr = wid >> 2, wc = wid & 3;  // 2 x 4 wave grid, 64x32 per wave

  // XCD-swizzled block id (M fast within an XCD chunk)
  const int nwg = gridDim.x * gridDim.y;
  const int wg = xcd_swizzle(blockIdx.y * gridDim.x + blockIdx.x, nwg);
  const size_t bm = (size_t)(wg & 63) * 128;   // gridDim.x == 64 (M blocks)
  const size_t bn = (size_t)(wg >> 6) * 128;

  const int srow = t >> 2, skc = (t & 3) * 8;  // 512 threads = one 128x32 tile
  const bf16* pa = A + (bm + srow) * HDIM + skc;
  const bf16* pg = Gt + (bn + srow) * HDIM + skc;
  const bf16* pu = Ut + (bn + srow) * HDIM + skc;
  const int fr = lane & 15, fq = lane >> 4;
  const int aoff = (wr * 64 + fr) * BK + fq * 8;
  const int boff = (wc * 32 + fr) * BK + fq * 8;

  f32x4 ag[4][2] = {};
  f32x4 au[4][2] = {};

#define STAGE_GU(buf, k0)                    \
  do {                                       \
    gload16(pa + (k0), &As[buf][t * 8]);     \
    gload16(pg + (k0), &Gs[buf][t * 8]);     \
    gload16(pu + (k0), &Us[buf][t * 8]);     \
  } while (0)

  int cur = 0;
  STAGE_GU(0, 0);
  __syncthreads();   // vmcnt(0) drain: buf0 ready
  for (int tt = 0; tt < NT; ++tt) {
    if (tt + 1 < NT) STAGE_GU(cur ^ 1, (tt + 1) * BK);  // prefetch in flight
    bf16x8 af[4], gf[2], uf[2];
#pragma unroll
    for (int m = 0; m < 4; ++m)
      af[m] = *(const bf16x8*)&As[cur][aoff + m * (16 * BK)];
#pragma unroll
    for (int n = 0; n < 2; ++n) {
      gf[n] = *(const bf16x8*)&Gs[cur][boff + n * (16 * BK)];
      uf[n] = *(const bf16x8*)&Us[cur][boff + n * (16 * BK)];
    }
#pragma unroll
    for (int m = 0; m < 4; ++m)
#pragma unroll
      for (int n = 0; n < 2; ++n) {
        ag[m][n] = mfma16(af[m], gf[n], ag[m][n]);
        au[m][n] = mfma16(af[m], uf[n], au[m][n]);
      }
    if (tt + 1 < NT) {
      __syncthreads();   // reads of cur done + prefetch landed
      cur ^= 1;
    }
  }
#undef STAGE_GU

  // epilogue: C/D layout col=lane&15, row=(lane>>4)*4+reg (m89-verified)
#pragma unroll
  for (int m = 0; m < 4; ++m) {
    const size_t rbase = bm + wr * 64 + m * 16 + fq * 4;
    float rwv[4];
#pragma unroll
    for (int j = 0; j < 4; ++j) rwv[j] = rwp[(rbase + j) * NEXP];
#pragma unroll
    for (int n = 0; n < 2; ++n) {
      const size_t col = bn + wc * 32 + n * 16 + fr;
#pragma unroll
      for (int j = 0; j < 4; ++j) {
        float g = ag[m][n][j];
        float u = au[m][n][j];
        float sil = g / (1.f + __expf(-g));
        out[(rbase + j) * (size_t)ldout + col] = (bf16)(sil * u * rwv[j]);
      }
    }
  }
}

// ---------------- down GEMM: out[M][1024] (+)= A[M][K] @ Bt[1024][K]^T -------
__global__ __launch_bounds__(512, 4) void gemm_down_kernel(
    const bf16* __restrict__ A, int lda, const bf16* __restrict__ Bt, int ldb,
    float* __restrict__ out, int K, int accumulate) {
  constexpr int BK = 32;
  __shared__ __align__(16) bf16 As[2][128 * BK];
  __shared__ __align__(16) bf16 Bs[2][128 * BK];
  const int t = threadIdx.x;
  const int lane = t & 63;
  const int wid = t >> 6;
  const int wr = wid >> 2, wc = wid & 3;

  const int nwg = gridDim.x * gridDim.y;
  const int wg = xcd_swizzle(blockIdx.y * gridDim.x + blockIdx.x, nwg);
  const size_t bm = (size_t)(wg & 63) * 128;   // gridDim.x == 64
  const size_t bn = (size_t)(wg >> 6) * 128;

  const int srow = t >> 2, skc = (t & 3) * 8;
  const bf16* pa = A + (bm + srow) * (size_t)lda + skc;
  const bf16* pb = Bt + (bn + srow) * (size_t)ldb + skc;
  const int fr = lane & 15, fq = lane >> 4;
  const int aoff = (wr * 64 + fr) * BK + fq * 8;
  const int boff = (wc * 32 + fr) * BK + fq * 8;

  f32x4 acc[4][2] = {};
  const int NT = K / BK;

#define STAGE_DN(buf, k0)                    \
  do {                                       \
    gload16(pa + (k0), &As[buf][t * 8]);     \
    gload16(pb + (k0), &Bs[buf][t * 8]);     \
  } while (0)

  int cur = 0;
  STAGE_DN(0, 0);
  __syncthreads();
  for (int tt = 0; tt < NT; ++tt) {
    if (tt + 1 < NT) STAGE_DN(cur ^ 1, (tt + 1) * BK);
    bf16x8 af[4], bfr[2];
#pragma unroll
    for (int m = 0; m < 4; ++m)
      af[m] = *(const bf16x8*)&As[cur][aoff + m * (16 * BK)];
#pragma unroll
    for (int n = 0; n < 2; ++n)
      bfr[n] = *(const bf16x8*)&Bs[cur][boff + n * (16 * BK)];
#pragma unroll
    for (int m = 0; m < 4; ++m)
#pragma unroll
      for (int n = 0; n < 2; ++n)
        acc[m][n] = mfma16(af[m], bfr[n], acc[m][n]);
    if (tt + 1 < NT) {
      __syncthreads();
      cur ^= 1;
    }
  }
#undef STAGE_DN

#pragma unroll
  for (int m = 0; m < 4; ++m) {
    const size_t rbase = bm + wr * 64 + m * 16 + fq * 4;
#pragma unroll
    for (int n = 0; n < 2; ++n) {
      const size_t col = bn + wc * 32 + n * 16 + fr;
#pragma unroll
      for (int j = 0; j < 4; ++j) {
        const size_t o = (rbase + j) * (size_t)HDIM + col;
        float v = acc[m][n][j];
        out[o] = accumulate ? (out[o] + v) : v;
      }
    }
  }
}

// -----------------------------------------------------------------------------
extern "C" void kernel_launch(void* const* d_in, const int* in_sizes, int n_in,
                              void* d_out, int out_size, void* d_ws, size_t ws_size,
                              hipStream_t stream) {
  const float* hs       = (const float*)d_in[0];
  const float* router_w = (const float*)d_in[1];
  const float* router_b = (const float*)d_in[2];
  const float* gate_w   = (const float*)d_in[3];
  const float* up_w     = (const float*)d_in[4];
  const float* down_w   = (const float*)d_in[5];
  float* out = (float*)d_out;

  const size_t KALL = (size_t)NEXP * IDIM;  // 22528

  char* ws = (char*)d_ws;
  size_t off = 0;
  auto alloc = [&](size_t bytes) -> void* {
    void* p = ws + off;
    off += (bytes + 255) & ~(size_t)255;
    return p;
  };

  float* rw    = (float*)alloc((size_t)MDIM * NEXP * 4);
  bf16* hsb    = (bf16*)alloc((size_t)MDIM * HDIM * 2);
  bf16* gate_t = (bf16*)alloc((size_t)IDIM * HDIM * 2);
  bf16* up_t   = (bf16*)alloc((size_t)IDIM * HDIM * 2);

  const size_t prefix = off;
  const size_t needA = prefix + (((size_t)HDIM * KALL * 2 + 255) & ~(size_t)255)
                              + (((size_t)MDIM * KALL * 2 + 255) & ~(size_t)255);
  const bool planA = (ws_size >= needA);

  // common: convert hs, router softmax, balance loss
  convert_hs_kernel<<<dim3((MDIM * HDIM) / (256 * 8)), dim3(256), 0, stream>>>(hs, hsb);
  router_kernel<<<dim3(MDIM / 4), dim3(256), 0, stream>>>(hs, router_w, router_b, rw);
  balance_kernel<<<dim3(1), dim3(256), 0, stream>>>(rw, out + (size_t)MDIM * HDIM);

  if (planA) {
    // single big-K down GEMM over concatenated (rw-scaled) gu'
    bf16* down_t = (bf16*)alloc((size_t)HDIM * KALL * 2);  // [H][E*I]
    bf16* gu     = (bf16*)alloc((size_t)MDIM * KALL * 2);  // [M][E*I]
    for (int e = 0; e < NEXP; ++e) {
      transpose_conv_kernel<<<dim3(IDIM / 32, HDIM / 32), dim3(32, 8), 0, stream>>>(
          gate_w + (size_t)e * HDIM * IDIM, gate_t, HDIM, IDIM, HDIM);
      transpose_conv_kernel<<<dim3(IDIM / 32, HDIM / 32), dim3(32, 8), 0, stream>>>(
          up_w + (size_t)e * HDIM * IDIM, up_t, HDIM, IDIM, HDIM);
      transpose_conv_kernel<<<dim3(HDIM / 32, IDIM / 32), dim3(32, 8), 0, stream>>>(
          down_w + (size_t)e * IDIM * HDIM, down_t + (size_t)e * IDIM, IDIM, HDIM, (int)KALL);
      gemm_gu_kernel<<<dim3(MDIM / 128, IDIM / 128), dim3(512), 0, stream>>>(
          hsb, gate_t, up_t, rw + e, gu + (size_t)e * IDIM, (int)KALL);
    }
    gemm_down_kernel<<<dim3(MDIM / 128, HDIM / 128), dim3(512), 0, stream>>>(
        gu, (int)KALL, down_t, (int)KALL, out, (int)KALL, 0);
  } else {
    // sequential experts, accumulate into memset output
    bf16* down_ts = (bf16*)alloc((size_t)HDIM * IDIM * 2);  // [H][I]
    bf16* gu      = (bf16*)alloc((size_t)MDIM * IDIM * 2);  // [M][I]
    hipMemsetAsync(out, 0, (size_t)MDIM * HDIM * 4, stream);
    for (int e = 0; e < NEXP; ++e) {
      transpose_conv_kernel<<<dim3(IDIM / 32, HDIM / 32), dim3(32, 8), 0, stream>>>(
          gate_w + (size_t)e * HDIM * IDIM, gate_t, HDIM, IDIM, HDIM);
      transpose_conv_kernel<<<dim3(IDIM / 32, HDIM / 32), dim3(32, 8), 0, stream>>>(
          up_w + (size_t)e * HDIM * IDIM, up_t, HDIM, IDIM, HDIM);
      transpose_conv_kernel<<<dim3(HDIM / 32, IDIM / 32), dim3(32, 8), 0, stream>>>(
          down_w + (size_t)e * IDIM * HDIM, down_ts, IDIM, HDIM, IDIM);
      gemm_gu_kernel<<<dim3(MDIM / 128, IDIM / 128), dim3(512), 0, stream>>>(
          hsb, gate_t, up_t, rw + e, gu, IDIM);
      gemm_down_kernel<<<dim3(MDIM / 128, HDIM / 128), dim3(512), 0, stream>>>(
          gu, IDIM, down_ts, IDIM, out, IDIM, 1);
    }
  }
  (void)in_sizes; (void)n_in; (void)out_size;
}